// Round 2
// baseline (174.658 us; speedup 1.0000x reference)
//
#include <hip/hip_runtime.h>

#define N_SEQ 8192
#define HDIM  128

typedef _Float16 half2v  __attribute__((ext_vector_type(2)));
typedef _Float16 half4v  __attribute__((ext_vector_type(4)));
typedef _Float16 half8v  __attribute__((ext_vector_type(8)));
typedef float    floatx16 __attribute__((ext_vector_type(16)));
typedef unsigned int uint32;

static_assert(sizeof(half8v) == 16, "half8v must be 16B");

// ---------------------------------------------------------------------------
// prep_k: K fp32 [N][D] -> f16 [N][D] row-major (contiguous k per row: A-frag ready)
// ---------------------------------------------------------------------------
__global__ void prep_k(const float* __restrict__ K, _Float16* __restrict__ K16) {
    int idx = blockIdx.x * 256 + threadIdx.x;        // N*D/4 = 262144 float4s
    float4 f = ((const float4*)K)[idx];
    half4v h;
    h[0] = (_Float16)f.x; h[1] = (_Float16)f.y;
    h[2] = (_Float16)f.z; h[3] = (_Float16)f.w;
    ((half4v*)K16)[idx] = h;
}

// ---------------------------------------------------------------------------
// prep_v: V fp32 [N][D] -> VT f16 tiled: VT[nt][d][nl], nt = n/32, nl = n%32.
// Tile is 128x32 halves = 8KB contiguous. Puts contraction dim (n) contiguous
// so PV A-fragments are 16B vector loads.
// ---------------------------------------------------------------------------
__global__ void prep_v(const float* __restrict__ V, _Float16* __restrict__ VTt) {
    __shared__ float lds[32 * 132];                  // 32 n-rows x (128+4) d
    const int t  = threadIdx.x;
    const int nt = blockIdx.x;                       // 256 tiles
    const int n0 = nt * 32;
    #pragma unroll
    for (int kk = 0; kk < 4; kk++) {
        int idx = t + 256 * kk;                      // 1024 float4s = 32x128 floats
        int nl = idx >> 5, c4 = idx & 31;
        float4 f = *(((const float4*)(V + (size_t)(n0 + nl) * HDIM)) + c4);
        float* dst = &lds[nl * 132 + c4 * 4];
        dst[0] = f.x; dst[1] = f.y; dst[2] = f.z; dst[3] = f.w;
    }
    __syncthreads();
    const int d = t & 127, hb = t >> 7;              // hb: which 16 of the 32 n
    half8v ha, hb2;
    #pragma unroll
    for (int ii = 0; ii < 8; ii++)  ha[ii]  = (_Float16)lds[(hb * 16 + ii) * 132 + d];
    #pragma unroll
    for (int ii = 0; ii < 8; ii++)  hb2[ii] = (_Float16)lds[(hb * 16 + 8 + ii) * 132 + d];
    _Float16* dst = VTt + (size_t)nt * (HDIM * 32) + d * 32 + hb * 16;
    *(half8v*)(dst)     = ha;
    *(half8v*)(dst + 8) = hb2;
}

// ---------------------------------------------------------------------------
// Main flash kernel. 4 waves x 32 query rows; BN=32 keys/iter.
// Computes S^T = K.Q^T via mfma_32x32x16_f16 so softmax state is per-lane.
// Writes unnormalized O^T partials + per-row (m, l) for the split-merge.
// ---------------------------------------------------------------------------
__launch_bounds__(256, 2)
__global__ void fa_main(const float* __restrict__ Qp, const _Float16* __restrict__ K16,
                        const _Float16* __restrict__ VTt, float* __restrict__ Opart,
                        float* __restrict__ lpart, float* __restrict__ mpart, int iters) {
    const int tid = threadIdx.x;
    const int lane = tid & 63;
    const int wv   = tid >> 6;
    const int l31  = lane & 31;
    const int q5   = lane >> 5;                      // 0/1 half-wave
    const int mt   = blockIdx.x;
    const int sp   = blockIdx.y;                     // split index
    const int m0   = mt * 128 + wv * 32;
    const float LOG2E = 1.44269504088896f;

    // Q B-fragments: B[k=d][col=m]: lane col = l31, k = kc*16 + q5*8 + j.
    // log2e folded in so scores land in exp2 domain.
    half8v qf[8];
    {
        const float* qrow = Qp + (size_t)(m0 + l31) * HDIM;
        #pragma unroll
        for (int kc = 0; kc < 8; kc++) {
            const float4 a = *(const float4*)(qrow + kc * 16 + q5 * 8);
            const float4 b = *(const float4*)(qrow + kc * 16 + q5 * 8 + 4);
            half8v h;
            h[0] = (_Float16)(a.x * LOG2E); h[1] = (_Float16)(a.y * LOG2E);
            h[2] = (_Float16)(a.z * LOG2E); h[3] = (_Float16)(a.w * LOG2E);
            h[4] = (_Float16)(b.x * LOG2E); h[5] = (_Float16)(b.y * LOG2E);
            h[6] = (_Float16)(b.z * LOG2E); h[7] = (_Float16)(b.w * LOG2E);
            qf[kc] = h;
        }
    }

    floatx16 oacc[4];                                // O^T acc: col = m = l31 for ALL regs
    #pragma unroll
    for (int dt = 0; dt < 4; dt++)
        #pragma unroll
        for (int r = 0; r < 16; r++) oacc[dt][r] = 0.0f;

    float runm = -3.0e38f;                           // running row max (exp2 units)
    float lsum = 0.0f;                               // this half-wave's partial row sum

    int nbase = sp * iters * 32;
    for (int it = 0; it < iters; ++it, nbase += 32) {
        // ---- S^T = K . Q^T : A-frag = K rows (lane = n), direct from global ----
        const _Float16* krow = K16 + (size_t)(nbase + l31) * HDIM + q5 * 8;
        floatx16 sacc;
        #pragma unroll
        for (int r = 0; r < 16; r++) sacc[r] = 0.0f;
        #pragma unroll
        for (int kc = 0; kc < 8; kc++) {
            half8v a = *(const half8v*)(krow + kc * 16);
            sacc = __builtin_amdgcn_mfma_f32_32x32x16_f16(a, qf[kc], sacc, 0, 0, 0);
        }
        // ---- online softmax, per-lane (lane's column = query row m) ----
        float cmax = sacc[0];
        #pragma unroll
        for (int r = 1; r < 16; r++) cmax = fmaxf(cmax, sacc[r]);
        cmax = fmaxf(cmax, __shfl_xor(cmax, 32, 64));      // other 16 n-rows
        const float mnew  = fmaxf(runm, cmax);
        const float alpha = __builtin_amdgcn_exp2f(runm - mnew);
        runm = mnew;
        float p[16];
        float ps = 0.0f;
        #pragma unroll
        for (int r = 0; r < 16; r++) {
            p[r] = __builtin_amdgcn_exp2f(sacc[r] - mnew);
            ps += p[r];
        }
        lsum = lsum * alpha + ps;
        #pragma unroll
        for (int dt = 0; dt < 4; dt++)
            #pragma unroll
            for (int r = 0; r < 16; r++) oacc[dt][r] *= alpha;

        // ---- P^T (C-layout) -> PV B-operand layout, in registers ----
        uint32 hpk[8];
        #pragma unroll
        for (int t2 = 0; t2 < 8; t2++) {
            auto pk = __builtin_amdgcn_cvt_pkrtz(p[2 * t2], p[2 * t2 + 1]);
            hpk[t2] = __builtin_bit_cast(uint32, pk);
        }
        const int nt = nbase >> 5;
        const _Float16* vbase = VTt + (size_t)nt * (HDIM * 32) + l31 * 32 + q5 * 8;
        #pragma unroll
        for (int kc2 = 0; kc2 < 2; kc2++) {
            // B[k=16*kc2+8*q5+j][m]: half from own regs, half from lane^32.
            uint32 pass0 = q5 ? hpk[4 * kc2 + 0] : hpk[4 * kc2 + 2];
            uint32 pass1 = q5 ? hpk[4 * kc2 + 1] : hpk[4 * kc2 + 3];
            uint32 r0 = (uint32)__shfl_xor((int)pass0, 32, 64);
            uint32 r1 = (uint32)__shfl_xor((int)pass1, 32, 64);
            uint32 b0 = q5 ? r0 : hpk[4 * kc2 + 0];
            uint32 b1 = q5 ? r1 : hpk[4 * kc2 + 1];
            uint32 b2 = q5 ? hpk[4 * kc2 + 2] : r0;
            uint32 b3 = q5 ? hpk[4 * kc2 + 3] : r1;
            uint4 bu = make_uint4(b0, b1, b2, b3);
            half8v bfrag = __builtin_bit_cast(half8v, bu);
            #pragma unroll
            for (int dt = 0; dt < 4; dt++) {
                half8v a = *(const half8v*)(vbase + dt * 32 * 32 + kc2 * 16);
                oacc[dt] = __builtin_amdgcn_mfma_f32_32x32x16_f16(a, bfrag, oacc[dt], 0, 0, 0);
            }
        }
    }

    // ---- epilogue: per-row (l, m) + unnormalized O^T partial ----
    float ltot = lsum + __shfl_xor(lsum, 32, 64);
    if (lane < 32) {
        lpart[(size_t)sp * N_SEQ + m0 + l31] = ltot;
        mpart[(size_t)sp * N_SEQ + m0 + l31] = runm;
    }
    #pragma unroll
    for (int dt = 0; dt < 4; dt++)
        #pragma unroll
        for (int r = 0; r < 16; r++) {
            int d = dt * 32 + (r & 3) + 8 * (r >> 2) + 4 * q5;
            Opart[((size_t)sp * HDIM + d) * N_SEQ + m0 + l31] = oacc[dt][r];
        }
}

// ---------------------------------------------------------------------------
// Merge: combine splits (rescale by exp2(m_s - M)), normalize, transpose to
// row-major out via LDS so the final store is coalesced.
// ---------------------------------------------------------------------------
__global__ void fa_merge(const float* __restrict__ Opart, const float* __restrict__ lpart,
                         const float* __restrict__ mpart, float* __restrict__ Out, int S) {
    __shared__ float lds[64 * 129];
    const int t = threadIdx.x;
    const int m0 = blockIdx.x * 64;
    const int i = t & 63;                            // m-local
    const int g = t >> 6;                            // d-group (32 each)
    const int m = m0 + i;

    float M = -3.0e38f;
    for (int s = 0; s < S; s++) M = fmaxf(M, mpart[(size_t)s * N_SEQ + m]);
    float L = 0.0f;
    for (int s = 0; s < S; s++)
        L += lpart[(size_t)s * N_SEQ + m] * __builtin_amdgcn_exp2f(mpart[(size_t)s * N_SEQ + m] - M);
    const float inv = 1.0f / L;

    float acc[32];
    #pragma unroll
    for (int dd = 0; dd < 32; dd++) acc[dd] = 0.0f;
    for (int s = 0; s < S; s++) {
        const float ww = __builtin_amdgcn_exp2f(mpart[(size_t)s * N_SEQ + m] - M) * inv;
        #pragma unroll
        for (int dd = 0; dd < 32; dd++) {
            int d = g * 32 + dd;
            acc[dd] += Opart[((size_t)s * HDIM + d) * N_SEQ + m] * ww;
        }
    }
    #pragma unroll
    for (int dd = 0; dd < 32; dd++) lds[i * 129 + g * 32 + dd] = acc[dd];
    __syncthreads();
    const int mi = t >> 2, c = t & 3;
    const float* row = &lds[mi * 129 + c * 32];
    float4* outp = (float4*)(Out + (size_t)(m0 + mi) * HDIM + c * 32);
    #pragma unroll
    for (int k2 = 0; k2 < 8; k2++) {
        float4 vv;
        vv.x = row[4 * k2]; vv.y = row[4 * k2 + 1];
        vv.z = row[4 * k2 + 2]; vv.w = row[4 * k2 + 3];
        outp[k2] = vv;
    }
}

// ---------------------------------------------------------------------------
// Safety-net: naive fp32 flash attention (one block per query row). Only used
// if ws_size is too small for the MFMA path.
// ---------------------------------------------------------------------------
__global__ void fa_naive(const float* __restrict__ Q, const float* __restrict__ K,
                         const float* __restrict__ V, float* __restrict__ O) {
    const int m = blockIdx.x;
    const int t = threadIdx.x;
    __shared__ float qs[HDIM];
    __shared__ float ps[256];
    __shared__ float red[256];
    if (t < HDIM) qs[t] = Q[(size_t)m * HDIM + t] * 1.44269504f;
    __syncthreads();
    float om = -3.0e38f, ls = 0.0f, oa = 0.0f;
    for (int nb = 0; nb < N_SEQ; nb += 256) {
        const float* kr = K + (size_t)(nb + t) * HDIM;
        float s = 0.0f;
        #pragma unroll 8
        for (int d = 0; d < HDIM; d++) s += qs[d] * kr[d];
        red[t] = s; __syncthreads();
        for (int st = 128; st > 0; st >>= 1) { if (t < st) red[t] = fmaxf(red[t], red[t + st]); __syncthreads(); }
        float cm = red[0];
        __syncthreads();
        float mn = fmaxf(om, cm);
        float al = __builtin_amdgcn_exp2f(om - mn);
        om = mn;
        float pp = __builtin_amdgcn_exp2f(s - mn);
        ps[t] = pp; red[t] = pp; __syncthreads();
        for (int st = 128; st > 0; st >>= 1) { if (t < st) red[t] += red[t + st]; __syncthreads(); }
        float csum = red[0];
        ls = ls * al + csum;
        if (t < HDIM) {
            float acc = 0.0f;
            for (int j = 0; j < 256; j++) acc += ps[j] * V[(size_t)(nb + j) * HDIM + t];
            oa = oa * al + acc;
        }
        __syncthreads();
    }
    if (t < HDIM) O[(size_t)m * HDIM + t] = oa / ls;
}

// ---------------------------------------------------------------------------
extern "C" void kernel_launch(void* const* d_in, const int* in_sizes, int n_in,
                              void* d_out, int out_size, void* d_ws, size_t ws_size,
                              hipStream_t stream) {
    const float* q = (const float*)d_in[0];
    const float* k = (const float*)d_in[1];
    const float* v = (const float*)d_in[2];
    float* out = (float*)d_out;

    const size_t MB = 1024ull * 1024ull;
    int S = 0;
    for (int s = 8; s >= 1; s >>= 1) {
        size_t need = 4 * MB + (size_t)s * (4 * MB + 64 * 1024);
        if (ws_size >= need) { S = s; break; }
    }
    if (S == 0) {                                    // workspace too small: slow-but-correct path
        fa_naive<<<N_SEQ, 256, 0, stream>>>(q, k, v, out);
        return;
    }
    char* ws = (char*)d_ws;
    _Float16* K16 = (_Float16*)ws;
    _Float16* VTt = (_Float16*)(ws + 2 * MB);
    float* Opart  = (float*)(ws + 4 * MB);
    float* lpart  = (float*)(ws + 4 * MB + (size_t)S * 4 * MB);
    float* mpart  = lpart + (size_t)S * N_SEQ;

    prep_k<<<dim3(N_SEQ * HDIM / 4 / 256), dim3(256), 0, stream>>>(k, K16);
    prep_v<<<dim3(N_SEQ / 32), dim3(256), 0, stream>>>(v, VTt);
    fa_main<<<dim3(N_SEQ / 128, S), dim3(256), 0, stream>>>(q, K16, VTt, Opart, lpart, mpart, 256 / S);
    fa_merge<<<dim3(N_SEQ / 64), dim3(256), 0, stream>>>(Opart, lpart, mpart, out, S);
}